// Round 7
// baseline (219.569 us; speedup 1.0000x reference)
//
#include <hip/hip_runtime.h>
#include <stdint.h>

// HeAttention, MI355X/gfx950 — Round 7: SINGLE persistent kernel.
//   Phase 1: q,k,vT,rkE,rqE projections (448 64x64 tiles over 256 blocks)
//   Phase 2: band-scores + softmax + PV (round-5 body; ctx -> ws bf16)
//   Phase 3: out = ctx * wo^T + bo (128 blocks, 32x64 tiles)
// Grid barriers: LDS 131840 B forces 1 block/CU; 256 blocks <= 256 CUs =>
// all co-resident => spin barrier is deadlock-free. Counters in ws are
// zeroed by block 0 behind a MAGIC flag (ws re-poisoned 0xAA every launch).
// B=1, S=512, D=512, H=8, hd=64, NE=1024. fp32 I/O, bf16 MFMA internally.

typedef __bf16 bf16_t;
typedef bf16_t bf16x8 __attribute__((ext_vector_type(8)));
typedef float f32x4 __attribute__((ext_vector_type(4)));

__device__ __forceinline__ uint16_t f2bf(float f) {
  union { float f; uint32_t i; } c; c.f = f;
  return (uint16_t)((c.i + 0x7fffu + ((c.i >> 16) & 1u)) >> 16);  // RNE
}
__device__ __forceinline__ uint32_t pack2bf(float lo, float hi) {
  return (uint32_t)f2bf(lo) | ((uint32_t)f2bf(hi) << 16);
}
#define MFMA(a, b, c) __builtin_amdgcn_mfma_f32_16x16x32_bf16((a), (b), (c), 0, 0, 0)

#define LSTR 40       // gemm LDS stride (bf16)
#define SSTR 72       // attn stride (bf16)
#define NBLK 256
#define BAR_MAGIC 0x1357A5A5

__device__ __forceinline__ void grid_bar(int* bar, int idx) {
  __syncthreads();
  if (threadIdx.x == 0) {
    __threadfence();  // release: drain stores, write back L2 (device scope)
    while (__hip_atomic_load(&bar[2], __ATOMIC_ACQUIRE, __HIP_MEMORY_SCOPE_AGENT) != BAR_MAGIC)
      __builtin_amdgcn_s_sleep(1);
    __hip_atomic_fetch_add(&bar[idx], 1, __ATOMIC_ACQ_REL, __HIP_MEMORY_SCOPE_AGENT);
    while (__hip_atomic_load(&bar[idx], __ATOMIC_ACQUIRE, __HIP_MEMORY_SCOPE_AGENT) < NBLK)
      __builtin_amdgcn_s_sleep(1);
    __threadfence();  // acquire: invalidate caches before consuming
  }
  __syncthreads();
  __threadfence();
}

__global__ __launch_bounds__(256, 1) void fused_all_kernel(
    const float* __restrict__ X, const float* __restrict__ emb,
    const float* __restrict__ wq, const float* __restrict__ bq,
    const float* __restrict__ wk, const float* __restrict__ bk,
    const float* __restrict__ wv, const float* __restrict__ bv,
    const float* __restrict__ wrk, const float* __restrict__ brk,
    const float* __restrict__ wrq, const float* __restrict__ brq,
    const float* __restrict__ wo, const float* __restrict__ bo,
    uint16_t* __restrict__ q, uint16_t* __restrict__ k, uint16_t* __restrict__ vT,
    uint16_t* __restrict__ rkE, uint16_t* __restrict__ rqE,
    uint16_t* __restrict__ ctx_bf, float* __restrict__ attn,
    float* __restrict__ outp, int* __restrict__ bar)
{
  __shared__ __align__(16) char smem[131840];
  const int bid = blockIdx.x;
  const int t = threadIdx.x, lane = t & 63, w = t >> 6;
  const int quad = lane >> 4, l15 = lane & 15;

  if (bid == 0 && t == 0) {
    __hip_atomic_store(&bar[0], 0, __ATOMIC_RELAXED, __HIP_MEMORY_SCOPE_AGENT);
    __hip_atomic_store(&bar[1], 0, __ATOMIC_RELAXED, __HIP_MEMORY_SCOPE_AGENT);
    __hip_atomic_store(&bar[2], BAR_MAGIC, __ATOMIC_RELEASE, __HIP_MEMORY_SCOPE_AGENT);
  }

  // ================= Phase 1: projections =================
  {
    uint16_t* As = (uint16_t*)smem;             // 64 x LSTR
    uint16_t* Bs = As + 64 * LSTR;              // 64 x LSTR
    const int wi = w & 1, wj = w >> 1;
    const int srow = t >> 2, scol = (t & 3) * 8;

    for (int u = bid; u < 448; u += NBLK) {
      int v = u;
      const float *A, *B, *bias; uint16_t* C; int mode;
      if (v < 64)       {           A = X;   B = wq;  bias = bq;  C = q;   mode = 2; }
      else if (v < 128) { v -= 64;  A = X;   B = wk;  bias = bk;  C = k;   mode = 2; }
      else if (v < 192) { v -= 128; A = X;   B = wv;  bias = bv;  C = vT;  mode = 3; }
      else if (v < 320) { v -= 192; A = emb; B = wrk; bias = brk; C = rkE; mode = 1; }
      else              { v -= 320; A = emb; B = wrq; bias = brq; C = rqE; mode = 1; }
      const int m0 = (v >> 3) * 64, n0 = (v & 7) * 64;

      f32x4 acc[2][2] = {};
      for (int k0 = 0; k0 < 512; k0 += 32) {
        const float* Af = A + (size_t)(m0 + srow) * 512 + (k0 + scol);
        const float* Bf = B + (size_t)(n0 + srow) * 512 + (k0 + scol);
        float4 a0 = *(const float4*)(Af), a1 = *(const float4*)(Af + 4);
        float4 b0 = *(const float4*)(Bf), b1 = *(const float4*)(Bf + 4);
        uint4 ap, bp;
        ap.x = pack2bf(a0.x, a0.y); ap.y = pack2bf(a0.z, a0.w);
        ap.z = pack2bf(a1.x, a1.y); ap.w = pack2bf(a1.z, a1.w);
        bp.x = pack2bf(b0.x, b0.y); bp.y = pack2bf(b0.z, b0.w);
        bp.z = pack2bf(b1.x, b1.y); bp.w = pack2bf(b1.z, b1.w);
        __syncthreads();  // WAR: previous iter/tile fragment reads done
        *(uint4*)(&As[srow * LSTR + scol]) = ap;
        *(uint4*)(&Bs[srow * LSTR + scol]) = bp;
        __syncthreads();
        bf16x8 af[2], bfr[2];
#pragma unroll
        for (int x = 0; x < 2; x++) {
          af[x]  = *(const bf16x8*)(&As[(wi * 32 + x * 16 + l15) * LSTR + quad * 8]);
          bfr[x] = *(const bf16x8*)(&Bs[(wj * 32 + x * 16 + l15) * LSTR + quad * 8]);
        }
#pragma unroll
        for (int x = 0; x < 2; x++)
#pragma unroll
          for (int y = 0; y < 2; y++)
            acc[x][y] = MFMA(af[x], bfr[y], acc[x][y]);
      }
#pragma unroll
      for (int x = 0; x < 2; x++)
#pragma unroll
        for (int y = 0; y < 2; y++) {
          const int j = n0 + wj * 32 + y * 16 + l15;
          const float bval = bias[j];
          const int ib = m0 + wi * 32 + x * 16 + quad * 4;
#pragma unroll
          for (int r = 0; r < 4; r++) {
            const int i = ib + r;
            size_t off;
            if (mode == 1)      off = (size_t)i * 512 + j;
            else if (mode == 2) off = (size_t)(j >> 6) * 32768 + (size_t)i * 64 + (size_t)(j & 63);
            else                off = (size_t)(j >> 6) * 32768 + (size_t)(j & 63) * 512 + (size_t)i;
            C[off] = f2bf(acc[x][y][r] + bval);
          }
        }
    }
  }
  grid_bar(bar, 0);

  // ================= Phase 2: scores + softmax + PV =================
  {
    const int h = bid & 7, i0 = (bid >> 3) * 16;   // h == XCD id: L2 locality
    uint16_t* stgw = (uint16_t*)smem + w * 16128;  // 224 x SSTR bf16
    float* U2f  = (float*)stgw;                    // 16 x 84
    float* U3f  = (float*)((char*)stgw + 5376);    // 80 x 68
    uint16_t* Pw = stgw;                           // 16 x SSTR
    float* ctxw = (float*)((char*)stgw + 8192);    // 16 x 64
    uint16_t* qs = (uint16_t*)(smem + 129024);     // 16 x SSTR
    float* rmax = (float*)(smem + 131328);         // [4][16]
    float* rsum = rmax + 64;                       // [4][16]

    if (t < 128) {
      const int row = t >> 3, col = (t & 7) * 8;
      *(uint4*)(&qs[row * SSTR + col]) =
          *(const uint4*)(q + (size_t)h * 32768 + (size_t)(i0 + row) * 64 + col);
    }

    f32x4 sc[2][4];
    const int jbase = w * 2;
#pragma unroll
    for (int jt2 = 0; jt2 < 2; jt2++) {
      const int j0 = (jbase + jt2) * 64;
      const int ebase = j0 - i0 + 497;   // in [1, 945]
      __syncthreads();                   // WAR vs prior diag reads; qs visibility
#pragma unroll
      for (int c = 0; c < 28; c++) {
        const int idx = lane + c * 64;
        const int row = idx >> 3, col = (idx & 7) * 8;
        const uint16_t* src;
        if (row < 64)       src = k   + (size_t)h * 32768 + (size_t)(j0 + row) * 64 + col;
        else if (row < 144) src = rqE + (size_t)min(ebase + row - 64, 1023) * 512 + h * 64 + col;
        else                src = rkE + (size_t)min(ebase + row - 144, 1023) * 512 + h * 64 + col;
        *(uint4*)(&stgw[row * SSTR + col]) = *(const uint4*)src;
      }
      __syncthreads();

      f32x4 acc1[4] = {}, acc2[5] = {}, acc3[5][4] = {};
#pragma unroll
      for (int s = 0; s < 2; s++) {
        const int ko = s * 32 + quad * 8;
        bf16x8 aq = *(const bf16x8*)(&qs[l15 * SSTR + ko]);
        bf16x8 bk[4], arq[5], brk[5];
#pragma unroll
        for (int tt = 0; tt < 4; tt++) bk[tt] = *(const bf16x8*)(&stgw[(tt * 16 + l15) * SSTR + ko]);
#pragma unroll
        for (int x = 0; x < 5; x++)    arq[x] = *(const bf16x8*)(&stgw[(64 + x * 16 + l15) * SSTR + ko]);
#pragma unroll
        for (int x = 0; x < 5; x++)    brk[x] = *(const bf16x8*)(&stgw[(144 + x * 16 + l15) * SSTR + ko]);
#pragma unroll
        for (int tt = 0; tt < 4; tt++) acc1[tt] = MFMA(aq, bk[tt], acc1[tt]);
#pragma unroll
        for (int x = 0; x < 5; x++)    acc2[x] = MFMA(aq, brk[x], acc2[x]);
#pragma unroll
        for (int x = 0; x < 5; x++)
#pragma unroll
          for (int tt = 0; tt < 4; tt++) acc3[x][tt] = MFMA(arq[x], bk[tt], acc3[x][tt]);
      }
      __syncthreads();   // staging reads done before U2/U3 overwrite
#pragma unroll
      for (int x = 0; x < 5; x++)
#pragma unroll
        for (int r = 0; r < 4; r++)
          U2f[(quad * 4 + r) * 84 + x * 16 + l15] = acc2[x][r];
#pragma unroll
      for (int x = 0; x < 5; x++)
#pragma unroll
        for (int tt = 0; tt < 4; tt++)
#pragma unroll
          for (int r = 0; r < 4; r++)
            U3f[(x * 16 + quad * 4 + r) * 68 + tt * 16 + l15] = acc3[x][tt][r];
      __syncthreads();
#pragma unroll
      for (int tt = 0; tt < 4; tt++)
#pragma unroll
        for (int r = 0; r < 4; r++) {
          const int ii = quad * 4 + r, jj = tt * 16 + l15;
          const int rb = jj - ii + 15;   // [0,78]
          sc[jt2][tt][r] = (acc1[tt][r] + U2f[ii * 84 + rb] + U3f[rb * 68 + jj]) * 0.125f;
        }
    }

    // softmax over j=512 (rows shared across the 4 waves)
    float mrow[4], srow[4];
#pragma unroll
    for (int r = 0; r < 4; r++) {
      float m = -1e30f;
#pragma unroll
      for (int jt2 = 0; jt2 < 2; jt2++)
#pragma unroll
        for (int tt = 0; tt < 4; tt++) m = fmaxf(m, sc[jt2][tt][r]);
#pragma unroll
      for (int o = 1; o < 16; o <<= 1) m = fmaxf(m, __shfl_xor(m, o, 64));
      mrow[r] = m;
    }
    if (l15 == 0)
#pragma unroll
      for (int r = 0; r < 4; r++) rmax[w * 16 + quad * 4 + r] = mrow[r];
    __syncthreads();
#pragma unroll
    for (int r = 0; r < 4; r++) {
      const int row = quad * 4 + r;
      const float m = fmaxf(fmaxf(rmax[row], rmax[16 + row]), fmaxf(rmax[32 + row], rmax[48 + row]));
      float s = 0.f;
#pragma unroll
      for (int jt2 = 0; jt2 < 2; jt2++)
#pragma unroll
        for (int tt = 0; tt < 4; tt++) {
          const float p = __expf(sc[jt2][tt][r] - m);
          sc[jt2][tt][r] = p; s += p;
        }
#pragma unroll
      for (int o = 1; o < 16; o <<= 1) s += __shfl_xor(s, o, 64);
      srow[r] = s;
    }
    if (l15 == 0)
#pragma unroll
      for (int r = 0; r < 4; r++) rsum[w * 16 + quad * 4 + r] = srow[r];
    __syncthreads();
#pragma unroll
    for (int r = 0; r < 4; r++) {
      const int row = quad * 4 + r;
      const float inv = 1.0f / (rsum[row] + rsum[16 + row] + rsum[32 + row] + rsum[48 + row]);
#pragma unroll
      for (int jt2 = 0; jt2 < 2; jt2++)
#pragma unroll
        for (int tt = 0; tt < 4; tt++) {
          sc[jt2][tt][r] *= inv;
          attn[((size_t)h * 512 + i0 + row) * 512 + (jbase + jt2) * 64 + tt * 16 + l15]
              = sc[jt2][tt][r];
        }
    }

    // PV: wave-partial ctx[16][64] over its 128 j, then cross-wave sum
    f32x4 apv[4] = {};
#pragma unroll
    for (int jt2 = 0; jt2 < 2; jt2++) {
      __syncthreads();
#pragma unroll
      for (int tt = 0; tt < 4; tt++)
#pragma unroll
        for (int r = 0; r < 4; r++)
          Pw[(quad * 4 + r) * SSTR + tt * 16 + l15] = f2bf(sc[jt2][tt][r]);
      __syncthreads();
#pragma unroll
      for (int s = 0; s < 2; s++) {
        const int ko = s * 32 + quad * 8;
        bf16x8 aP = *(const bf16x8*)(&Pw[l15 * SSTR + ko]);
#pragma unroll
        for (int tt = 0; tt < 4; tt++) {
          bf16x8 bv = *(const bf16x8*)(vT + (size_t)h * 32768 + (size_t)(tt * 16 + l15) * 512
                                       + (jbase + jt2) * 64 + ko);
          apv[tt] = MFMA(aP, bv, apv[tt]);
        }
      }
    }
#pragma unroll
    for (int tt = 0; tt < 4; tt++)
#pragma unroll
      for (int r = 0; r < 4; r++)
        ctxw[(quad * 4 + r) * 64 + tt * 16 + l15] = apv[tt][r];
    __syncthreads();
    {
      const int row = t >> 4, col = (t & 15) * 4;
      const size_t off = (size_t)(row * 64 + col) * 4;
      float4 s0 = *(const float4*)(smem + 0 * 32256 + 8192 + off);
      float4 s1 = *(const float4*)(smem + 1 * 32256 + 8192 + off);
      float4 s2 = *(const float4*)(smem + 2 * 32256 + 8192 + off);
      float4 s3 = *(const float4*)(smem + 3 * 32256 + 8192 + off);
      uint2 pk;
      pk.x = pack2bf(s0.x + s1.x + s2.x + s3.x, s0.y + s1.y + s2.y + s3.y);
      pk.y = pack2bf(s0.z + s1.z + s2.z + s3.z, s0.w + s1.w + s2.w + s3.w);
      *(uint2*)(ctx_bf + (size_t)(i0 + row) * 512 + h * 64 + col) = pk;
    }
  }
  grid_bar(bar, 1);

  // ================= Phase 3: out = ctx * wo^T + bo =================
  if (bid < 128) {
    uint16_t* As = (uint16_t*)smem;             // 32 x LSTR (ctx bf16)
    uint16_t* Bs = As + 32 * LSTR;              // 64 x LSTR (wo -> bf16)
    const int m0 = (bid >> 3) * 32, n0 = (bid & 7) * 64;
    const int wm = w & 1, wn = w >> 1;
    const int srow = t >> 2, scol = (t & 3) * 8;

    f32x4 acc[2] = {};
    for (int k0 = 0; k0 < 512; k0 += 32) {
      uint4 ap;
      if (t < 128)
        ap = *(const uint4*)(ctx_bf + (size_t)(m0 + srow) * 512 + (k0 + scol));
      const float* Bf = wo + (size_t)(n0 + srow) * 512 + (k0 + scol);
      float4 b0 = *(const float4*)(Bf), b1 = *(const float4*)(Bf + 4);
      uint4 bp;
      bp.x = pack2bf(b0.x, b0.y); bp.y = pack2bf(b0.z, b0.w);
      bp.z = pack2bf(b1.x, b1.y); bp.w = pack2bf(b1.z, b1.w);
      __syncthreads();
      if (t < 128) *(uint4*)(&As[srow * LSTR + scol]) = ap;
      *(uint4*)(&Bs[srow * LSTR + scol]) = bp;
      __syncthreads();
      bf16x8 af = *(const bf16x8*)(&As[(wm * 16 + l15) * LSTR + quad * 8]);
#pragma unroll
      for (int y = 0; y < 2; y++) {
        bf16x8 bfr = *(const bf16x8*)(&Bs[(wn * 32 + y * 16 + l15) * LSTR + quad * 8]);
        acc[y] = MFMA(af, bfr, acc[y]);
      }
    }
#pragma unroll
    for (int y = 0; y < 2; y++) {
      const int j = n0 + wn * 32 + y * 16 + l15;
      const float bval = bo[j];
      const int ib = m0 + wm * 16 + quad * 4;
#pragma unroll
      for (int r = 0; r < 4; r++)
        outp[(size_t)(ib + r) * 512 + j] = acc[y][r] + bval;
    }
  }
}

extern "C" void kernel_launch(void* const* d_in, const int* in_sizes, int n_in,
                              void* d_out, int out_size, void* d_ws, size_t ws_size,
                              hipStream_t stream) {
  const float* X   = (const float*)d_in[0];
  const float* emb = (const float*)d_in[1];
  const float* wq  = (const float*)d_in[2];
  const float* bq  = (const float*)d_in[3];
  const float* wk  = (const float*)d_in[4];
  const float* bk  = (const float*)d_in[5];
  const float* wv  = (const float*)d_in[6];
  const float* bv  = (const float*)d_in[7];
  const float* wrk = (const float*)d_in[8];
  const float* brk = (const float*)d_in[9];
  const float* wrq = (const float*)d_in[10];
  const float* brq = (const float*)d_in[11];
  const float* wo  = (const float*)d_in[12];
  const float* bo  = (const float*)d_in[13];

  // ws layout (uint16 elems): 4 MB tensors + barrier ints at tail
  uint16_t* q      = (uint16_t*)d_ws;         // [8][512][64]
  uint16_t* k      = q   + 262144;            // [8][512][64]
  uint16_t* vT     = k   + 262144;            // [8][64][512]
  uint16_t* rkE    = vT  + 262144;            // [1024][512]
  uint16_t* rqE    = rkE + 524288;            // [1024][512]
  uint16_t* ctx_bf = rqE + 524288;            // [512][512]
  int*      bar    = (int*)(ctx_bf + 262144); // [3]: bar0, bar1, magic-flag

  float* outp = (float*)d_out;                // [512][512]
  float* attn = (float*)d_out + 262144;       // [8][512][512]

  fused_all_kernel<<<dim3(NBLK), dim3(256), 0, stream>>>(
      X, emb, wq, bq, wk, bk, wv, bv, wrk, brk, wrq, brq, wo, bo,
      q, k, vT, rkE, rqE, ctx_bf, attn, outp, bar);
}

// Round 8
// 123.608 us; speedup vs baseline: 1.7763x; 1.7763x over previous
//
#include <hip/hip_runtime.h>
#include <stdint.h>

// HeAttention, MI355X/gfx950 — Round 8: 3 launches, lean bodies.
//   L1 proj: q,k,vT,rkE,rqE projections (448 blocks, pipelined loads).
//   L2 attn: 256 blocks x 512 thr (8 waves = 2/SIMD). Scores/PV fragments
//      read DIRECTLY from global (no LDS staging); LDS only for the U2/U3
//      diagonal round-trip (fp16), P tile, ctx partials. 5 barriers total.
//   L3 out = ctx * wo^T + bo (64 blocks, pipelined loads).
// B=1, S=512, D=512, H=8, hd=64, NE=1024. fp32 I/O, bf16 MFMA internally.

typedef __bf16 bf16_t;
typedef bf16_t bf16x8 __attribute__((ext_vector_type(8)));
typedef float f32x4 __attribute__((ext_vector_type(4)));

__device__ __forceinline__ uint16_t f2bf(float f) {
  union { float f; uint32_t i; } c; c.f = f;
  return (uint16_t)((c.i + 0x7fffu + ((c.i >> 16) & 1u)) >> 16);  // RNE
}
__device__ __forceinline__ uint32_t pack2bf(float lo, float hi) {
  return (uint32_t)f2bf(lo) | ((uint32_t)f2bf(hi) << 16);
}
#define MFMA(a, b, c) __builtin_amdgcn_mfma_f32_16x16x32_bf16((a), (b), (c), 0, 0, 0)

#define LSTR 40   // proj/out LDS stride (bf16)
#define SSTR 72   // P-tile stride (bf16)
#define RGN  13568  // attn per-wave LDS region bytes

// ---------------- fused projections (pipelined) ----------------
__global__ __launch_bounds__(256) void proj_kernel(
    const float* __restrict__ X, const float* __restrict__ emb,
    const float* __restrict__ wq, const float* __restrict__ bq,
    const float* __restrict__ wk, const float* __restrict__ bk,
    const float* __restrict__ wv, const float* __restrict__ bv,
    const float* __restrict__ wrk, const float* __restrict__ brk,
    const float* __restrict__ wrq, const float* __restrict__ brq,
    uint16_t* __restrict__ q, uint16_t* __restrict__ k, uint16_t* __restrict__ vT,
    uint16_t* __restrict__ rkE, uint16_t* __restrict__ rqE)
{
  int bid = blockIdx.x;
  const float *A, *B, *bias; uint16_t* C; int mode;
  if (bid < 64)       {            A = X;   B = wq;  bias = bq;  C = q;   mode = 2; }
  else if (bid < 128) { bid -= 64; A = X;   B = wk;  bias = bk;  C = k;   mode = 2; }
  else if (bid < 192) { bid -= 128; A = X;  B = wv;  bias = bv;  C = vT;  mode = 3; }
  else if (bid < 320) { bid -= 192; A = emb; B = wrk; bias = brk; C = rkE; mode = 1; }
  else                { bid -= 320; A = emb; B = wrq; bias = brq; C = rqE; mode = 1; }
  const int m0 = (bid >> 3) * 64, n0 = (bid & 7) * 64;

  __shared__ __align__(16) uint16_t As[64 * LSTR];
  __shared__ __align__(16) uint16_t Bs[64 * LSTR];
  const int t = threadIdx.x, lane = t & 63, wave = t >> 6;
  const int wi = wave & 1, wj = wave >> 1;
  const int quad = lane >> 4, l15 = lane & 15;
  const int srow = t >> 2, scol = (t & 3) * 8;

  const float* Af = A + (size_t)(m0 + srow) * 512 + scol;
  const float* Bf = B + (size_t)(n0 + srow) * 512 + scol;
  float4 a0 = *(const float4*)(Af), a1 = *(const float4*)(Af + 4);
  float4 b0 = *(const float4*)(Bf), b1 = *(const float4*)(Bf + 4);

  f32x4 acc[2][2] = {};
  for (int k0 = 0; k0 < 512; k0 += 32) {
    uint4 ap, bp;
    ap.x = pack2bf(a0.x, a0.y); ap.y = pack2bf(a0.z, a0.w);
    ap.z = pack2bf(a1.x, a1.y); ap.w = pack2bf(a1.z, a1.w);
    bp.x = pack2bf(b0.x, b0.y); bp.y = pack2bf(b0.z, b0.w);
    bp.z = pack2bf(b1.x, b1.y); bp.w = pack2bf(b1.z, b1.w);
    __syncthreads();   // WAR: prior frag reads done
    *(uint4*)(&As[srow * LSTR + scol]) = ap;
    *(uint4*)(&Bs[srow * LSTR + scol]) = bp;
    __syncthreads();
    if (k0 < 480) {    // prefetch next k-step during MFMA
      a0 = *(const float4*)(Af + k0 + 32); a1 = *(const float4*)(Af + k0 + 36);
      b0 = *(const float4*)(Bf + k0 + 32); b1 = *(const float4*)(Bf + k0 + 36);
    }
    bf16x8 af[2], bfr[2];
#pragma unroll
    for (int x = 0; x < 2; x++) {
      af[x]  = *(const bf16x8*)(&As[(wi * 32 + x * 16 + l15) * LSTR + quad * 8]);
      bfr[x] = *(const bf16x8*)(&Bs[(wj * 32 + x * 16 + l15) * LSTR + quad * 8]);
    }
#pragma unroll
    for (int x = 0; x < 2; x++)
#pragma unroll
      for (int y = 0; y < 2; y++)
        acc[x][y] = MFMA(af[x], bfr[y], acc[x][y]);
  }
#pragma unroll
  for (int x = 0; x < 2; x++)
#pragma unroll
    for (int y = 0; y < 2; y++) {
      const int j = n0 + wj * 32 + y * 16 + l15;
      const float bval = bias[j];
      const int ib = m0 + wi * 32 + x * 16 + quad * 4;
#pragma unroll
      for (int r = 0; r < 4; r++) {
        const int i = ib + r;
        size_t off;
        if (mode == 1)      off = (size_t)i * 512 + j;
        else if (mode == 2) off = (size_t)(j >> 6) * 32768 + (size_t)i * 64 + (size_t)(j & 63);
        else                off = (size_t)(j >> 6) * 32768 + (size_t)(j & 63) * 512 + (size_t)i;
        C[off] = f2bf(acc[x][y][r] + bval);
      }
    }
}

// ---------------- attn: scores + softmax + PV, stage-free ----------------
// Block (i-strip 16 rows, h); wave w of 8 owns j-tile j0 = w*64.
// Frags straight from global; per-wave LDS region (RGN B):
//   U2h fp16 16x84 @+0 | U3h fp16 80x68 @+2688 | P bf16 16xSSTR @+0 (PV)
//   | ctx partial f32 16x64 @+4096. Tail: rmax/rsum [8][16] f32.
// score(ii,jj) = S1 + U2[ii,rb] + U3[rb,jj], rb = jj-ii+15 in [0,78];
// band base e = j0-i0+497 in [1,945] (clamped garbage row 79 never read).
__global__ __launch_bounds__(512, 2) void attn_kernel(
    const uint16_t* __restrict__ q, const uint16_t* __restrict__ k,
    const uint16_t* __restrict__ rkE, const uint16_t* __restrict__ rqE,
    const uint16_t* __restrict__ vT,
    float* __restrict__ attn, uint16_t* __restrict__ ctx_bf)
{
  __shared__ __align__(16) char smem[8 * RGN + 1024];
  const int h = blockIdx.y, i0 = blockIdx.x * 16;
  const int t = threadIdx.x, lane = t & 63, w = t >> 6;
  const int quad = lane >> 4, l15 = lane & 15;
  const int j0 = w * 64;
  const int ebase = j0 - i0 + 497;

  char* rgn = smem + w * RGN;
  _Float16* U2h = (_Float16*)rgn;              // 16 x 84
  _Float16* U3h = (_Float16*)(rgn + 2688);     // 80 x 68
  uint16_t* Pw  = (uint16_t*)rgn;              // 16 x SSTR (PV phase)
  float*    ctxw = (float*)(rgn + 4096);       // 16 x 64   (epilogue)
  float* rmax = (float*)(smem + 8 * RGN);      // [8][16]
  float* rsum = rmax + 128;                    // [8][16]

  const uint16_t* qh = q  + (size_t)h * 32768;
  const uint16_t* kh = k  + (size_t)h * 32768;
  const uint16_t* vh = vT + (size_t)h * 32768;

  // ---- scores: S1 = q k^T, U2 = q rk_band^T, U3 = rq_band k^T ----
  f32x4 acc1[4] = {}, acc2[5] = {}, acc3[5][4] = {};
#pragma unroll
  for (int s = 0; s < 2; s++) {
    const int ko = s * 32 + quad * 8;
    bf16x8 aq = *(const bf16x8*)(qh + (size_t)(i0 + l15) * 64 + ko);
    bf16x8 bk[4], arq[5], brk[5];
#pragma unroll
    for (int tt = 0; tt < 4; tt++)
      bk[tt] = *(const bf16x8*)(kh + (size_t)(j0 + tt * 16 + l15) * 64 + ko);
#pragma unroll
    for (int x = 0; x < 5; x++) {
      const int e = min(ebase + x * 16 + l15, 1023);
      arq[x] = *(const bf16x8*)(rqE + (size_t)e * 512 + h * 64 + ko);
      brk[x] = *(const bf16x8*)(rkE + (size_t)e * 512 + h * 64 + ko);
    }
#pragma unroll
    for (int tt = 0; tt < 4; tt++) acc1[tt] = MFMA(aq, bk[tt], acc1[tt]);
#pragma unroll
    for (int x = 0; x < 5; x++)    acc2[x] = MFMA(aq, brk[x], acc2[x]);
#pragma unroll
    for (int x = 0; x < 5; x++)
#pragma unroll
      for (int tt = 0; tt < 4; tt++) acc3[x][tt] = MFMA(arq[x], bk[tt], acc3[x][tt]);
  }
  // U round-trip (wave-private, fp16; HW keeps per-wave LDS order)
#pragma unroll
  for (int x = 0; x < 5; x++)
#pragma unroll
    for (int r = 0; r < 4; r++)
      U2h[(quad * 4 + r) * 84 + x * 16 + l15] = (_Float16)acc2[x][r];
#pragma unroll
  for (int x = 0; x < 5; x++)
#pragma unroll
    for (int tt = 0; tt < 4; tt++)
#pragma unroll
      for (int r = 0; r < 4; r++)
        U3h[(x * 16 + quad * 4 + r) * 68 + tt * 16 + l15] = (_Float16)acc3[x][tt][r];
  __syncthreads();  // #1 (ordering safety)

  f32x4 sc[4];
#pragma unroll
  for (int tt = 0; tt < 4; tt++)
#pragma unroll
    for (int r = 0; r < 4; r++) {
      const int ii = quad * 4 + r, jj = tt * 16 + l15;
      const int rb = jj - ii + 15;   // [0,78]
      sc[tt][r] = (acc1[tt][r] + (float)U2h[ii * 84 + rb] + (float)U3h[rb * 68 + jj]) * 0.125f;
    }

  // ---- softmax over j=512 (8 waves share each row) ----
  float mrow[4];
#pragma unroll
  for (int r = 0; r < 4; r++) {
    float m = fmaxf(fmaxf(sc[0][r], sc[1][r]), fmaxf(sc[2][r], sc[3][r]));
#pragma unroll
    for (int o = 1; o < 16; o <<= 1) m = fmaxf(m, __shfl_xor(m, o, 64));
    mrow[r] = m;
  }
  if (l15 == 0)
#pragma unroll
    for (int r = 0; r < 4; r++) rmax[w * 16 + quad * 4 + r] = mrow[r];
  __syncthreads();  // #2
  float srow[4];
#pragma unroll
  for (int r = 0; r < 4; r++) {
    const int row = quad * 4 + r;
    float m = rmax[row];
#pragma unroll
    for (int x = 1; x < 8; x++) m = fmaxf(m, rmax[x * 16 + row]);
    float s = 0.f;
#pragma unroll
    for (int tt = 0; tt < 4; tt++) {
      const float p = __expf(sc[tt][r] - m);
      sc[tt][r] = p; s += p;
    }
#pragma unroll
    for (int o = 1; o < 16; o <<= 1) s += __shfl_xor(s, o, 64);
    srow[r] = s;
  }
  if (l15 == 0)
#pragma unroll
    for (int r = 0; r < 4; r++) rsum[w * 16 + quad * 4 + r] = srow[r];
  __syncthreads();  // #3
#pragma unroll
  for (int r = 0; r < 4; r++) {
    const int row = quad * 4 + r;
    float s = rsum[row];
#pragma unroll
    for (int x = 1; x < 8; x++) s += rsum[x * 16 + row];
    const float inv = 1.0f / s;
#pragma unroll
    for (int tt = 0; tt < 4; tt++) {
      sc[tt][r] *= inv;
      attn[((size_t)h * 512 + i0 + row) * 512 + j0 + tt * 16 + l15] = sc[tt][r];
    }
  }

  // ---- PV: wave-partial ctx[16][64] over this wave's 64 j ----
#pragma unroll
  for (int tt = 0; tt < 4; tt++)
#pragma unroll
    for (int r = 0; r < 4; r++)
      Pw[(quad * 4 + r) * SSTR + tt * 16 + l15] = f2bf(sc[tt][r]);
  __syncthreads();  // #4 (ordering safety)
  f32x4 apv[4] = {};
#pragma unroll
  for (int s = 0; s < 2; s++) {
    const int ko = s * 32 + quad * 8;
    bf16x8 aP = *(const bf16x8*)(&Pw[l15 * SSTR + ko]);
#pragma unroll
    for (int tt = 0; tt < 4; tt++) {
      bf16x8 bv = *(const bf16x8*)(vh + (size_t)(tt * 16 + l15) * 512 + j0 + ko);
      apv[tt] = MFMA(aP, bv, apv[tt]);
    }
  }
#pragma unroll
  for (int tt = 0; tt < 4; tt++)
#pragma unroll
    for (int r = 0; r < 4; r++)
      ctxw[(quad * 4 + r) * 64 + tt * 16 + l15] = apv[tt][r];
  __syncthreads();  // #5
  // cross-wave ctx sum (512 thr x 2 floats) -> ctx_bf
  {
    const int idx = t * 2, row = idx >> 6, col = idx & 63;
    const size_t off = 4096 + (size_t)(row * 64 + col) * 4;
    float c0 = 0.f, c1 = 0.f;
#pragma unroll
    for (int x = 0; x < 8; x++) {
      float2 v = *(const float2*)(smem + x * RGN + off);
      c0 += v.x; c1 += v.y;
    }
    *(uint32_t*)(ctx_bf + (size_t)(i0 + row) * 512 + h * 64 + col) = pack2bf(c0, c1);
  }
}

// ---------------- out = ctx * wo^T + bo (pipelined) ----------------
__global__ __launch_bounds__(256) void out_kernel(
    const uint16_t* __restrict__ ctx_bf, const float* __restrict__ wo,
    const float* __restrict__ bo, float* __restrict__ outp)
{
  __shared__ __align__(16) uint16_t As[64 * LSTR];
  __shared__ __align__(16) uint16_t Bs[64 * LSTR];
  const int m0 = blockIdx.y * 64, n0 = blockIdx.x * 64;
  const int t = threadIdx.x, lane = t & 63, wave = t >> 6;
  const int wi = wave & 1, wj = wave >> 1;
  const int quad = lane >> 4, l15 = lane & 15;
  const int srow = t >> 2, scol = (t & 3) * 8;

  const uint16_t* Af = ctx_bf + (size_t)(m0 + srow) * 512 + scol;
  const float* Bf = wo + (size_t)(n0 + srow) * 512 + scol;
  uint4 ap = *(const uint4*)(Af);
  float4 b0 = *(const float4*)(Bf), b1 = *(const float4*)(Bf + 4);

  f32x4 acc[2][2] = {};
  for (int k0 = 0; k0 < 512; k0 += 32) {
    uint4 bp;
    bp.x = pack2bf(b0.x, b0.y); bp.y = pack2bf(b0.z, b0.w);
    bp.z = pack2bf(b1.x, b1.y); bp.w = pack2bf(b1.z, b1.w);
    uint4 apc = ap;
    __syncthreads();
    *(uint4*)(&As[srow * LSTR + scol]) = apc;
    *(uint4*)(&Bs[srow * LSTR + scol]) = bp;
    __syncthreads();
    if (k0 < 480) {
      ap = *(const uint4*)(Af + k0 + 32);
      b0 = *(const float4*)(Bf + k0 + 32); b1 = *(const float4*)(Bf + k0 + 36);
    }
    bf16x8 af[2], bfr[2];
#pragma unroll
    for (int x = 0; x < 2; x++) {
      af[x]  = *(const bf16x8*)(&As[(wi * 32 + x * 16 + l15) * LSTR + quad * 8]);
      bfr[x] = *(const bf16x8*)(&Bs[(wj * 32 + x * 16 + l15) * LSTR + quad * 8]);
    }
#pragma unroll
    for (int x = 0; x < 2; x++)
#pragma unroll
      for (int y = 0; y < 2; y++)
        acc[x][y] = MFMA(af[x], bfr[y], acc[x][y]);
  }
#pragma unroll
  for (int x = 0; x < 2; x++)
#pragma unroll
    for (int y = 0; y < 2; y++) {
      const int j = n0 + wj * 32 + y * 16 + l15;
      const float bval = bo[j];
      const int ib = m0 + wi * 32 + x * 16 + quad * 4;
#pragma unroll
      for (int r = 0; r < 4; r++)
        outp[(size_t)(ib + r) * 512 + j] = acc[x][y][r] + bval;
    }
}

extern "C" void kernel_launch(void* const* d_in, const int* in_sizes, int n_in,
                              void* d_out, int out_size, void* d_ws, size_t ws_size,
                              hipStream_t stream) {
  const float* X   = (const float*)d_in[0];
  const float* emb = (const float*)d_in[1];
  const float* wq  = (const float*)d_in[2];
  const float* bq  = (const float*)d_in[3];
  const float* wk  = (const float*)d_in[4];
  const float* bk  = (const float*)d_in[5];
  const float* wv  = (const float*)d_in[6];
  const float* bv  = (const float*)d_in[7];
  const float* wrk = (const float*)d_in[8];
  const float* brk = (const float*)d_in[9];
  const float* wrq = (const float*)d_in[10];
  const float* brq = (const float*)d_in[11];
  const float* wo  = (const float*)d_in[12];
  const float* bo  = (const float*)d_in[13];

  // ws layout (uint16 elems, ~4.2 MB):
  uint16_t* q      = (uint16_t*)d_ws;         // [8][512][64]
  uint16_t* k      = q   + 262144;            // [8][512][64]
  uint16_t* vT     = k   + 262144;            // [8][64][512]
  uint16_t* rkE    = vT  + 262144;            // [1024][512]
  uint16_t* rqE    = rkE + 524288;            // [1024][512]
  uint16_t* ctx_bf = rqE + 524288;            // [512][512]

  float* outp = (float*)d_out;                // [512][512]
  float* attn = (float*)d_out + 262144;       // [8][512][512]

  proj_kernel<<<dim3(448), dim3(256), 0, stream>>>(X, emb, wq, bq, wk, bk, wv, bv,
                                                   wrk, brk, wrq, brq, q, k, vT, rkE, rqE);
  attn_kernel<<<dim3(32, 8), dim3(512), 0, stream>>>(q, k, rkE, rqE, vT, attn, ctx_bf);
  out_kernel<<<dim3(8, 8), dim3(256), 0, stream>>>(ctx_bf, wo, bo, outp);
}

// Round 9
// 120.072 us; speedup vs baseline: 1.8286x; 1.0295x over previous
//
#include <hip/hip_runtime.h>
#include <stdint.h>

// HeAttention, MI355X/gfx950 — Round 9: HW bf16 packed converts + wider out.
//   L1 proj: q,k,vT,rkE,rqE projections (448 blocks, pipelined loads).
//   L2 attn: 256 blocks x 512 thr; frags straight from global; LDS only for
//      U2/U3 fp16 diagonal round-trip, P tile, ctx partials (round-8 body).
//   L3 out = ctx * wo^T + bo (128 blocks, 32x64 tiles, pipelined).
// fp32 I/O, bf16 MFMA internally; conversions via __builtin_convertvector
// (RNE; lowers to packed v_cvt on gfx950 instead of ~7-op bit-twiddle).
// B=1, S=512, D=512, H=8, hd=64, NE=1024.

typedef __bf16 bf16_t;
typedef bf16_t bf16x8 __attribute__((ext_vector_type(8)));
typedef float f32x4 __attribute__((ext_vector_type(4)));
typedef float f32x2v __attribute__((ext_vector_type(2)));
typedef bf16_t bf16x2v __attribute__((ext_vector_type(2)));

__device__ __forceinline__ uint16_t f2bf(float f) {
  bf16_t b = (bf16_t)f;                       // compiler RNE (HW cvt on gfx950)
  union { bf16_t b; uint16_t u; } c; c.b = b; return c.u;
}
__device__ __forceinline__ uint32_t cvt2(float lo, float hi) {
  bf16x2v v = __builtin_convertvector((f32x2v){lo, hi}, bf16x2v);
  union { bf16x2v v; uint32_t u; } c; c.v = v; return c.u;
}
__device__ __forceinline__ uint4 cvt8(float4 a, float4 b) {
  uint4 r;
  r.x = cvt2(a.x, a.y); r.y = cvt2(a.z, a.w);
  r.z = cvt2(b.x, b.y); r.w = cvt2(b.z, b.w);
  return r;
}
#define MFMA(a, b, c) __builtin_amdgcn_mfma_f32_16x16x32_bf16((a), (b), (c), 0, 0, 0)

#define LSTR 40     // proj/out LDS stride (bf16)
#define SSTR 72     // P-tile stride (bf16)
#define RGN  13568  // attn per-wave LDS region bytes

// ---------------- fused projections (pipelined) ----------------
__global__ __launch_bounds__(256) void proj_kernel(
    const float* __restrict__ X, const float* __restrict__ emb,
    const float* __restrict__ wq, const float* __restrict__ bq,
    const float* __restrict__ wk, const float* __restrict__ bk,
    const float* __restrict__ wv, const float* __restrict__ bv,
    const float* __restrict__ wrk, const float* __restrict__ brk,
    const float* __restrict__ wrq, const float* __restrict__ brq,
    uint16_t* __restrict__ q, uint16_t* __restrict__ k, uint16_t* __restrict__ vT,
    uint16_t* __restrict__ rkE, uint16_t* __restrict__ rqE)
{
  int bid = blockIdx.x;
  const float *A, *B, *bias; uint16_t* C; int mode;
  if (bid < 64)       {            A = X;   B = wq;  bias = bq;  C = q;   mode = 2; }
  else if (bid < 128) { bid -= 64; A = X;   B = wk;  bias = bk;  C = k;   mode = 2; }
  else if (bid < 192) { bid -= 128; A = X;  B = wv;  bias = bv;  C = vT;  mode = 3; }
  else if (bid < 320) { bid -= 192; A = emb; B = wrk; bias = brk; C = rkE; mode = 1; }
  else                { bid -= 320; A = emb; B = wrq; bias = brq; C = rqE; mode = 1; }
  const int m0 = (bid >> 3) * 64, n0 = (bid & 7) * 64;

  __shared__ __align__(16) uint16_t As[64 * LSTR];
  __shared__ __align__(16) uint16_t Bs[64 * LSTR];
  const int t = threadIdx.x, lane = t & 63, wave = t >> 6;
  const int wi = wave & 1, wj = wave >> 1;
  const int quad = lane >> 4, l15 = lane & 15;
  const int srow = t >> 2, scol = (t & 3) * 8;

  const float* Af = A + (size_t)(m0 + srow) * 512 + scol;
  const float* Bf = B + (size_t)(n0 + srow) * 512 + scol;
  float4 a0 = *(const float4*)(Af), a1 = *(const float4*)(Af + 4);
  float4 b0 = *(const float4*)(Bf), b1 = *(const float4*)(Bf + 4);

  f32x4 acc[2][2] = {};
  for (int k0 = 0; k0 < 512; k0 += 32) {
    const uint4 ap = cvt8(a0, a1);
    const uint4 bp = cvt8(b0, b1);
    __syncthreads();   // WAR: prior frag reads done
    *(uint4*)(&As[srow * LSTR + scol]) = ap;
    *(uint4*)(&Bs[srow * LSTR + scol]) = bp;
    __syncthreads();
    if (k0 < 480) {    // prefetch next k-step during MFMA
      a0 = *(const float4*)(Af + k0 + 32); a1 = *(const float4*)(Af + k0 + 36);
      b0 = *(const float4*)(Bf + k0 + 32); b1 = *(const float4*)(Bf + k0 + 36);
    }
    bf16x8 af[2], bfr[2];
#pragma unroll
    for (int x = 0; x < 2; x++) {
      af[x]  = *(const bf16x8*)(&As[(wi * 32 + x * 16 + l15) * LSTR + quad * 8]);
      bfr[x] = *(const bf16x8*)(&Bs[(wj * 32 + x * 16 + l15) * LSTR + quad * 8]);
    }
#pragma unroll
    for (int x = 0; x < 2; x++)
#pragma unroll
      for (int y = 0; y < 2; y++)
        acc[x][y] = MFMA(af[x], bfr[y], acc[x][y]);
  }
#pragma unroll
  for (int x = 0; x < 2; x++)
#pragma unroll
    for (int y = 0; y < 2; y++) {
      const int j = n0 + wj * 32 + y * 16 + l15;
      const float bval = bias[j];
      const int ib = m0 + wi * 32 + x * 16 + quad * 4;
#pragma unroll
      for (int r = 0; r < 4; r++) {
        const int i = ib + r;
        size_t off;
        if (mode == 1)      off = (size_t)i * 512 + j;
        else if (mode == 2) off = (size_t)(j >> 6) * 32768 + (size_t)i * 64 + (size_t)(j & 63);
        else                off = (size_t)(j >> 6) * 32768 + (size_t)(j & 63) * 512 + (size_t)i;
        C[off] = f2bf(acc[x][y][r] + bval);
      }
    }
}

// ---------------- attn: scores + softmax + PV, stage-free ----------------
// Block (i-strip 16 rows, h); wave w of 8 owns j-tile j0 = w*64.
// Frags straight from global; per-wave LDS region (RGN B):
//   U2h fp16 16x84 @+0 | U3h fp16 80x68 @+2688 | P bf16 16xSSTR @+0 (PV)
//   | ctx partial f32 16x64 @+4096. Tail: rmax/rsum [8][16] f32.
// score(ii,jj) = S1 + U2[ii,rb] + U3[rb,jj], rb = jj-ii+15 in [0,78];
// band base e = j0-i0+497 in [1,945] (clamped garbage row 79 never read).
__global__ __launch_bounds__(512, 2) void attn_kernel(
    const uint16_t* __restrict__ q, const uint16_t* __restrict__ k,
    const uint16_t* __restrict__ rkE, const uint16_t* __restrict__ rqE,
    const uint16_t* __restrict__ vT,
    float* __restrict__ attn, uint16_t* __restrict__ ctx_bf)
{
  __shared__ __align__(16) char smem[8 * RGN + 1024];
  const int h = blockIdx.y, i0 = blockIdx.x * 16;
  const int t = threadIdx.x, lane = t & 63, w = t >> 6;
  const int quad = lane >> 4, l15 = lane & 15;
  const int j0 = w * 64;
  const int ebase = j0 - i0 + 497;

  char* rgn = smem + w * RGN;
  _Float16* U2h = (_Float16*)rgn;              // 16 x 84
  _Float16* U3h = (_Float16*)(rgn + 2688);     // 80 x 68
  uint16_t* Pw  = (uint16_t*)rgn;              // 16 x SSTR (PV phase)
  float*    ctxw = (float*)(rgn + 4096);       // 16 x 64   (epilogue)
  float* rmax = (float*)(smem + 8 * RGN);      // [8][16]
  float* rsum = rmax + 128;                    // [8][16]

  const uint16_t* qh = q  + (size_t)h * 32768;
  const uint16_t* kh = k  + (size_t)h * 32768;
  const uint16_t* vh = vT + (size_t)h * 32768;

  // ---- scores: S1 = q k^T, U2 = q rk_band^T, U3 = rq_band k^T ----
  f32x4 acc1[4] = {}, acc2[5] = {}, acc3[5][4] = {};
#pragma unroll
  for (int s = 0; s < 2; s++) {
    const int ko = s * 32 + quad * 8;
    bf16x8 aq = *(const bf16x8*)(qh + (size_t)(i0 + l15) * 64 + ko);
    bf16x8 bk[4], arq[5], brk[5];
#pragma unroll
    for (int tt = 0; tt < 4; tt++)
      bk[tt] = *(const bf16x8*)(kh + (size_t)(j0 + tt * 16 + l15) * 64 + ko);
#pragma unroll
    for (int x = 0; x < 5; x++) {
      const int e = min(ebase + x * 16 + l15, 1023);
      arq[x] = *(const bf16x8*)(rqE + (size_t)e * 512 + h * 64 + ko);
      brk[x] = *(const bf16x8*)(rkE + (size_t)e * 512 + h * 64 + ko);
    }
#pragma unroll
    for (int tt = 0; tt < 4; tt++) acc1[tt] = MFMA(aq, bk[tt], acc1[tt]);
#pragma unroll
    for (int x = 0; x < 5; x++)    acc2[x] = MFMA(aq, brk[x], acc2[x]);
#pragma unroll
    for (int x = 0; x < 5; x++)
#pragma unroll
      for (int tt = 0; tt < 4; tt++) acc3[x][tt] = MFMA(arq[x], bk[tt], acc3[x][tt]);
  }
  // U round-trip (wave-private, fp16)
#pragma unroll
  for (int x = 0; x < 5; x++)
#pragma unroll
    for (int r = 0; r < 4; r++)
      U2h[(quad * 4 + r) * 84 + x * 16 + l15] = (_Float16)acc2[x][r];
#pragma unroll
  for (int x = 0; x < 5; x++)
#pragma unroll
    for (int tt = 0; tt < 4; tt++)
#pragma unroll
      for (int r = 0; r < 4; r++)
        U3h[(x * 16 + quad * 4 + r) * 68 + tt * 16 + l15] = (_Float16)acc3[x][tt][r];
  __syncthreads();  // #1 (ordering safety)

  f32x4 sc[4];
#pragma unroll
  for (int tt = 0; tt < 4; tt++)
#pragma unroll
    for (int r = 0; r < 4; r++) {
      const int ii = quad * 4 + r, jj = tt * 16 + l15;
      const int rb = jj - ii + 15;   // [0,78]
      sc[tt][r] = (acc1[tt][r] + (float)U2h[ii * 84 + rb] + (float)U3h[rb * 68 + jj]) * 0.125f;
    }

  // ---- softmax over j=512 (8 waves share each row) ----
  float mrow[4];
#pragma unroll
  for (int r = 0; r < 4; r++) {
    float m = fmaxf(fmaxf(sc[0][r], sc[1][r]), fmaxf(sc[2][r], sc[3][r]));
#pragma unroll
    for (int o = 1; o < 16; o <<= 1) m = fmaxf(m, __shfl_xor(m, o, 64));
    mrow[r] = m;
  }
  if (l15 == 0)
#pragma unroll
    for (int r = 0; r < 4; r++) rmax[w * 16 + quad * 4 + r] = mrow[r];
  __syncthreads();  // #2
  float srow[4];
#pragma unroll
  for (int r = 0; r < 4; r++) {
    const int row = quad * 4 + r;
    float m = rmax[row];
#pragma unroll
    for (int x = 1; x < 8; x++) m = fmaxf(m, rmax[x * 16 + row]);
    float s = 0.f;
#pragma unroll
    for (int tt = 0; tt < 4; tt++) {
      const float p = __expf(sc[tt][r] - m);
      sc[tt][r] = p; s += p;
    }
#pragma unroll
    for (int o = 1; o < 16; o <<= 1) s += __shfl_xor(s, o, 64);
    srow[r] = s;
  }
  if (l15 == 0)
#pragma unroll
    for (int r = 0; r < 4; r++) rsum[w * 16 + quad * 4 + r] = srow[r];
  __syncthreads();  // #3
#pragma unroll
  for (int r = 0; r < 4; r++) {
    const int row = quad * 4 + r;
    float s = rsum[row];
#pragma unroll
    for (int x = 1; x < 8; x++) s += rsum[x * 16 + row];
    const float inv = 1.0f / s;
#pragma unroll
    for (int tt = 0; tt < 4; tt++) {
      sc[tt][r] *= inv;
      attn[((size_t)h * 512 + i0 + row) * 512 + j0 + tt * 16 + l15] = sc[tt][r];
    }
  }

  // ---- PV: wave-partial ctx[16][64] over this wave's 64 j ----
#pragma unroll
  for (int tt = 0; tt < 4; tt++)
#pragma unroll
    for (int r = 0; r < 4; r++)
      Pw[(quad * 4 + r) * SSTR + tt * 16 + l15] = f2bf(sc[tt][r]);
  __syncthreads();  // #4 (ordering safety)
  f32x4 apv[4] = {};
#pragma unroll
  for (int s = 0; s < 2; s++) {
    const int ko = s * 32 + quad * 8;
    bf16x8 aP = *(const bf16x8*)(&Pw[l15 * SSTR + ko]);
#pragma unroll
    for (int tt = 0; tt < 4; tt++) {
      bf16x8 bv = *(const bf16x8*)(vh + (size_t)(tt * 16 + l15) * 512 + j0 + ko);
      apv[tt] = MFMA(aP, bv, apv[tt]);
    }
  }
#pragma unroll
  for (int tt = 0; tt < 4; tt++)
#pragma unroll
    for (int r = 0; r < 4; r++)
      ctxw[(quad * 4 + r) * 64 + tt * 16 + l15] = apv[tt][r];
  __syncthreads();  // #5
  // cross-wave ctx sum (512 thr x 2 floats) -> ctx_bf
  {
    const int idx = t * 2, row = idx >> 6, col = idx & 63;
    const size_t off = 4096 + (size_t)(row * 64 + col) * 4;
    float c0 = 0.f, c1 = 0.f;
#pragma unroll
    for (int x = 0; x < 8; x++) {
      float2 v = *(const float2*)(smem + x * RGN + off);
      c0 += v.x; c1 += v.y;
    }
    *(uint32_t*)(ctx_bf + (size_t)(i0 + row) * 512 + h * 64 + col) = cvt2(c0, c1);
  }
}

// ---------------- out = ctx * wo^T + bo (128 blocks, 32x64 tiles) ----------------
__global__ __launch_bounds__(256) void out_kernel(
    const uint16_t* __restrict__ ctx_bf, const float* __restrict__ wo,
    const float* __restrict__ bo, float* __restrict__ outp)
{
  __shared__ __align__(16) uint16_t As[32 * LSTR];
  __shared__ __align__(16) uint16_t Bs[64 * LSTR];
  const int m0 = blockIdx.y * 32, n0 = blockIdx.x * 64;
  const int t = threadIdx.x, lane = t & 63, wave = t >> 6;
  const int wm = wave & 1, wn = wave >> 1;
  const int quad = lane >> 4, l15 = lane & 15;
  const int srow = t >> 2, scol = (t & 3) * 8;

  const uint16_t* Af = ctx_bf + (size_t)(m0 + (srow & 31)) * 512 + scol;
  const float* Bf = wo + (size_t)(n0 + srow) * 512 + scol;
  uint4 ap = *(const uint4*)(Af);
  float4 b0 = *(const float4*)(Bf), b1 = *(const float4*)(Bf + 4);

  f32x4 acc[2] = {};
  for (int k0 = 0; k0 < 512; k0 += 32) {
    const uint4 bp = cvt8(b0, b1);
    const uint4 apc = ap;
    __syncthreads();
    if (t < 128) *(uint4*)(&As[srow * LSTR + scol]) = apc;
    *(uint4*)(&Bs[srow * LSTR + scol]) = bp;
    __syncthreads();
    if (k0 < 480) {
      ap = *(const uint4*)(Af + k0 + 32);
      b0 = *(const float4*)(Bf + k0 + 32); b1 = *(const float4*)(Bf + k0 + 36);
    }
    bf16x8 af = *(const bf16x8*)(&As[(wm * 16 + l15) * LSTR + quad * 8]);
#pragma unroll
    for (int y = 0; y < 2; y++) {
      bf16x8 bfr = *(const bf16x8*)(&Bs[(wn * 32 + y * 16 + l15) * LSTR + quad * 8]);
      acc[y] = MFMA(af, bfr, acc[y]);
    }
  }
#pragma unroll
  for (int y = 0; y < 2; y++) {
    const int j = n0 + wn * 32 + y * 16 + l15;
    const float bval = bo[j];
    const int ib = m0 + wm * 16 + quad * 4;
#pragma unroll
    for (int r = 0; r < 4; r++)
      outp[(size_t)(ib + r) * 512 + j] = acc[y][r] + bval;
  }
}

extern "C" void kernel_launch(void* const* d_in, const int* in_sizes, int n_in,
                              void* d_out, int out_size, void* d_ws, size_t ws_size,
                              hipStream_t stream) {
  const float* X   = (const float*)d_in[0];
  const float* emb = (const float*)d_in[1];
  const float* wq  = (const float*)d_in[2];
  const float* bq  = (const float*)d_in[3];
  const float* wk  = (const float*)d_in[4];
  const float* bk  = (const float*)d_in[5];
  const float* wv  = (const float*)d_in[6];
  const float* bv  = (const float*)d_in[7];
  const float* wrk = (const float*)d_in[8];
  const float* brk = (const float*)d_in[9];
  const float* wrq = (const float*)d_in[10];
  const float* brq = (const float*)d_in[11];
  const float* wo  = (const float*)d_in[12];
  const float* bo  = (const float*)d_in[13];

  // ws layout (uint16 elems, ~4.2 MB):
  uint16_t* q      = (uint16_t*)d_ws;         // [8][512][64]
  uint16_t* k      = q   + 262144;            // [8][512][64]
  uint16_t* vT     = k   + 262144;            // [8][64][512]
  uint16_t* rkE    = vT  + 262144;            // [1024][512]
  uint16_t* rqE    = rkE + 524288;            // [1024][512]
  uint16_t* ctx_bf = rqE + 524288;            // [512][512]

  float* outp = (float*)d_out;                // [512][512]
  float* attn = (float*)d_out + 262144;       // [8][512][512]

  proj_kernel<<<dim3(448), dim3(256), 0, stream>>>(X, emb, wq, bq, wk, bk, wv, bv,
                                                   wrk, brk, wrq, brq, q, k, vT, rkE, rqE);
  attn_kernel<<<dim3(32, 8), dim3(512), 0, stream>>>(q, k, rkE, rqE, vT, attn, ctx_bf);
  out_kernel<<<dim3(8, 16), dim3(256), 0, stream>>>(ctx_bf, wo, bo, outp);
}